// Round 6
// baseline (790.838 us; speedup 1.0000x reference)
//
#include <hip/hip_runtime.h>

// Problem constants (fixed by the reference)
#define D        64
#define V        1024
#define HQ       4
#define M_TOTAL  131072      // 32 * 4096 rows
#define MR       128         // rows per block
#define NT       256         // threads per block
#define TAU      4e-3f       // near-tie rescue threshold (bf16-split fast-path err <~6e-4)
#define LOSS_SCALE (1.25f / 8388608.0f)
#define RT_STRIDE 68         // 64 + 4 pad (keeps rows 16B-aligned)

typedef __attribute__((ext_vector_type(8))) short short8;
typedef __attribute__((ext_vector_type(4))) float f32x4;

// ---- ordered-float <-> uint transforms (ascending float == ascending uint) ----
__device__ __forceinline__ unsigned int f2ord(float f) {
  unsigned int b = __float_as_uint(f);
  return b ^ (((unsigned int)((int)b >> 31)) | 0x80000000u);
}
__device__ __forceinline__ float ord2f(unsigned int u) {
  unsigned int b = u ^ ((~((unsigned int)((int)u >> 31))) | 0x80000000u);
  return __uint_as_float(b);
}
// bf16 round-to-nearest-even
__device__ __forceinline__ unsigned short f2bf(float f) {
  unsigned int u = __float_as_uint(f);
  return (unsigned short)((u + 0x7fffu + ((u >> 16) & 1u)) >> 16);
}

// ---- prep: split codebook into bf16 hi/lo in MFMA-fragment order, w2, zero loss ----
// Fragment layout (short8 units within a stage): unit = ((ct*2+kk)*2+hl)*64 + lane,
// holding W[code=ct*16+(lane&15)][k=kk*32+(lane>>4)*8 + j], j=0..7 as bf16.
__global__ void vq_prep(const float* __restrict__ emb, unsigned short* __restrict__ Wfrag,
                        float* __restrict__ W2, float* __restrict__ out) {
  int t = blockIdx.x * NT + threadIdx.x;   // over HQ*V = 4096
  if (t == 0) out[0] = 0.0f;
  if (t >= HQ * V) return;
  int s = t >> 10, v = t & (V - 1);
  int ct = v >> 4, cl = v & 15;
  const float* e = emb + (size_t)t * D;
  float w2 = 0.0f;
  for (int k = 0; k < D; ++k) {
    float f = e[k];
    w2 += f * f;
    unsigned short hb = f2bf(f);
    float fh = __uint_as_float((unsigned int)hb << 16);
    unsigned short lb = f2bf(f - fh);
    int kk = k >> 5, q = (k >> 3) & 3, j = k & 7;
    size_t base = (((size_t)(s * 64 + ct) * 2 + kk) * 2) * 512
                + (size_t)(q * 16 + cl) * 8 + j;
    Wfrag[base]       = hb;   // hl = 0
    Wfrag[base + 512] = lb;   // hl = 1
  }
  W2[t] = w2;
}

// ---- main kernel: 128 rows/block, 4 waves, MFMA bf16-split, B direct from global ----
__launch_bounds__(NT, 4)
__global__ void vq_main(const float* __restrict__ latent,
                        const float* __restrict__ emb,
                        const unsigned short* __restrict__ Wfrag,
                        const float* __restrict__ W2,
                        float* __restrict__ out) {
  __shared__ float Rt[MR][RT_STRIDE];   // 34.8 KB fp32 residual
  __shared__ int idx_lds[MR];
  __shared__ int n_rescue;
  __shared__ int rescue_rows[MR];
  __shared__ float resc_d2f[NT];
  __shared__ int   resc_ixs[NT];
  __shared__ float loss_red[NT];

  const int t    = threadIdx.x;
  const int lane = t & 63;
  const int w    = t >> 6;       // wave id: rows [w*32, w*32+32)
  const int cl   = lane & 15;
  const int q    = lane >> 4;
  const size_t row0 = (size_t)blockIdx.x * MR;

  if (t == 0) n_rescue = 0;

  // ---- load latent tile -> Rt (coalesced float4) ----
  {
    const float4* lg = (const float4*)(latent + row0 * D);
    #pragma unroll
    for (int k = 0; k < 8; ++k) {
      int i4 = t + k * NT;
      int row = i4 >> 4, dd = (i4 & 15) * 4;
      *(float4*)&Rt[row][dd] = lg[i4];
    }
  }

  float loss_acc = 0.0f;

  for (int stage = 0; stage < HQ; ++stage) {
    __syncthreads();           // Rt ready (initial load or previous stage's update)

    // ---- build A fragments (bf16 hi/lo) from Rt ----
    short8 Ah[2][2], Al[2][2];
    #pragma unroll
    for (int rt = 0; rt < 2; ++rt)
      #pragma unroll
      for (int kk = 0; kk < 2; ++kk) {
        const float* rp = &Rt[w * 32 + rt * 16 + cl][kk * 32 + q * 8];
        short8 h, l;
        #pragma unroll
        for (int j = 0; j < 8; ++j) {
          float f = rp[j];
          unsigned short hb = f2bf(f);
          float fh = __uint_as_float((unsigned int)hb << 16);
          h[j] = (short)hb;
          l[j] = (short)f2bf(f - fh);
        }
        Ah[rt][kk] = h; Al[rt][kk] = l;
      }

    // per-lane top-2: slot (rt,r) covers row = w*32+rt*16+q*4+r, cols ≡ cl (mod 16)
    float m1[2][4], m2[2][4]; int i1[2][4];
    #pragma unroll
    for (int rt = 0; rt < 2; ++rt)
      #pragma unroll
      for (int r = 0; r < 4; ++r) { m1[rt][r] = INFINITY; m2[rt][r] = INFINITY; i1[rt][r] = 0; }

    const short8* wb = (const short8*)(Wfrag + (size_t)stage * 131072);
    const float* w2p = W2 + stage * V;

    // ---- ct loop: 64 code-tiles, 2-deep ping-pong B prefetch, no barriers ----
    short8 B0[4], B1[4]; float w2a, w2b;
    {
      int base = lane;
      B0[0] = wb[base]; B0[1] = wb[base + 64]; B0[2] = wb[base + 128]; B0[3] = wb[base + 192];
      w2a = w2p[cl];
    }
    #pragma unroll 1
    for (int ct = 0; ct < 64; ct += 2) {
      {   // prefetch ct+1
        int base = (ct + 1) * 256 + lane;
        B1[0] = wb[base]; B1[1] = wb[base + 64]; B1[2] = wb[base + 128]; B1[3] = wb[base + 192];
        w2b = w2p[(ct + 1) * 16 + cl];
      }
      {   // compute ct with B0
        int code = ct * 16 + cl;
        #pragma unroll
        for (int rt = 0; rt < 2; ++rt) {
          f32x4 C1 = {0.f,0.f,0.f,0.f}, C2 = {0.f,0.f,0.f,0.f};
          C1 = __builtin_amdgcn_mfma_f32_16x16x32_bf16(Ah[rt][0], B0[0], C1, 0, 0, 0);
          C1 = __builtin_amdgcn_mfma_f32_16x16x32_bf16(Ah[rt][1], B0[2], C1, 0, 0, 0);
          C2 = __builtin_amdgcn_mfma_f32_16x16x32_bf16(Al[rt][0], B0[0], C2, 0, 0, 0);
          C2 = __builtin_amdgcn_mfma_f32_16x16x32_bf16(Al[rt][1], B0[2], C2, 0, 0, 0);
          C2 = __builtin_amdgcn_mfma_f32_16x16x32_bf16(Ah[rt][0], B0[1], C2, 0, 0, 0);
          C2 = __builtin_amdgcn_mfma_f32_16x16x32_bf16(Ah[rt][1], B0[3], C2, 0, 0, 0);
          #pragma unroll
          for (int r = 0; r < 4; ++r) {
            float s = fmaf(-2.0f, C1[r] + C2[r], w2a);
            m2[rt][r] = fminf(m2[rt][r], fmaxf(s, m1[rt][r]));
            bool lt = s < m1[rt][r];
            m1[rt][r] = fminf(m1[rt][r], s);
            i1[rt][r] = lt ? code : i1[rt][r];
          }
        }
      }
      {   // prefetch ct+2 (clamped dup at the tail: harmless)
        int ctn = (ct + 2 < 64) ? ct + 2 : 63;
        int base = ctn * 256 + lane;
        B0[0] = wb[base]; B0[1] = wb[base + 64]; B0[2] = wb[base + 128]; B0[3] = wb[base + 192];
        w2a = w2p[ctn * 16 + cl];
      }
      {   // compute ct+1 with B1
        int code = (ct + 1) * 16 + cl;
        #pragma unroll
        for (int rt = 0; rt < 2; ++rt) {
          f32x4 C1 = {0.f,0.f,0.f,0.f}, C2 = {0.f,0.f,0.f,0.f};
          C1 = __builtin_amdgcn_mfma_f32_16x16x32_bf16(Ah[rt][0], B1[0], C1, 0, 0, 0);
          C1 = __builtin_amdgcn_mfma_f32_16x16x32_bf16(Ah[rt][1], B1[2], C1, 0, 0, 0);
          C2 = __builtin_amdgcn_mfma_f32_16x16x32_bf16(Al[rt][0], B1[0], C2, 0, 0, 0);
          C2 = __builtin_amdgcn_mfma_f32_16x16x32_bf16(Al[rt][1], B1[2], C2, 0, 0, 0);
          C2 = __builtin_amdgcn_mfma_f32_16x16x32_bf16(Ah[rt][0], B1[1], C2, 0, 0, 0);
          C2 = __builtin_amdgcn_mfma_f32_16x16x32_bf16(Ah[rt][1], B1[3], C2, 0, 0, 0);
          #pragma unroll
          for (int r = 0; r < 4; ++r) {
            float s = fmaf(-2.0f, C1[r] + C2[r], w2b);
            m2[rt][r] = fminf(m2[rt][r], fmaxf(s, m1[rt][r]));
            bool lt = s < m1[rt][r];
            m1[rt][r] = fminf(m1[rt][r], s);
            i1[rt][r] = lt ? code : i1[rt][r];
          }
        }
      }
    } // ct

    // ---- 16-lane butterfly top-2 reduction ----
    #pragma unroll
    for (int rt = 0; rt < 2; ++rt)
      #pragma unroll
      for (int r = 0; r < 4; ++r) {
        unsigned int phi = f2ord(m1[rt][r]);
        unsigned int plo = (unsigned int)i1[rt][r];
        unsigned int s2  = f2ord(m2[rt][r]);
        #pragma unroll
        for (int mask = 1; mask <= 8; mask <<= 1) {
          unsigned int ohi = (unsigned int)__shfl_xor((int)phi, mask, 16);
          unsigned int olo = (unsigned int)__shfl_xor((int)plo, mask, 16);
          unsigned int os2 = (unsigned int)__shfl_xor((int)s2, mask, 16);
          unsigned long long p  = ((unsigned long long)phi << 32) | plo;
          unsigned long long po = ((unsigned long long)ohi << 32) | olo;
          unsigned int hmax = phi > ohi ? phi : ohi;
          s2 = s2 < os2 ? s2 : os2;
          s2 = s2 < hmax ? s2 : hmax;
          unsigned long long pm = p < po ? p : po;   // ties -> smaller idx (first index)
          phi = (unsigned int)(pm >> 32); plo = (unsigned int)pm;
        }
        if (cl == 0) {
          int row = w * 32 + rt * 16 + q * 4 + r;
          idx_lds[row] = (int)plo;
          float gap = ord2f(s2) - ord2f(phi);
          if (gap < TAU) {
            int slot = atomicAdd(&n_rescue, 1);
            rescue_rows[slot] = row;
          }
        }
      }
    __syncthreads();   // idx_lds + rescue flags visible
    int nres = n_rescue;
    __syncthreads();   // all reads of n_rescue done
    if (t == 0) n_rescue = 0;  // for next stage; ordered before next adds by stage-top barrier

    // ---- near-tie rescue: bit-exact numpy-reference emulation (verified R4/R5) ----
    for (int rr_i = 0; rr_i < nres; ++rr_i) {
      int row = rescue_rows[rr_i];
      float p8[8];
      #pragma unroll
      for (int j = 0; j < 8; ++j) p8[j] = __fmul_rn(Rt[row][j], Rt[row][j]);
      #pragma unroll
      for (int i = 1; i < 8; ++i)
        #pragma unroll
        for (int j = 0; j < 8; ++j)
          p8[j] = __fadd_rn(p8[j], __fmul_rn(Rt[row][8 * i + j], Rt[row][8 * i + j]));
      float rrow = __fadd_rn(__fadd_rn(__fadd_rn(p8[0], p8[1]), __fadd_rn(p8[2], p8[3])),
                             __fadd_rn(__fadd_rn(p8[4], p8[5]), __fadd_rn(p8[6], p8[7])));
      const float* eb = emb + (size_t)stage * V * D;
      float bestd = INFINITY; int besti = 0;
      #pragma unroll
      for (int c = 0; c < 4; ++c) {
        int v = t * 4 + c;
        const float* wv = eb + (size_t)v * D;
        float dot = 0.0f;
        #pragma unroll
        for (int d = 0; d < D; ++d) dot = __fmaf_rn(Rt[row][d], wv[d], dot);
        float q8[8];
        #pragma unroll
        for (int j = 0; j < 8; ++j) q8[j] = __fmul_rn(wv[j], wv[j]);
        #pragma unroll
        for (int i = 1; i < 8; ++i)
          #pragma unroll
          for (int j = 0; j < 8; ++j)
            q8[j] = __fadd_rn(q8[j], __fmul_rn(wv[8 * i + j], wv[8 * i + j]));
        float w2e = __fadd_rn(__fadd_rn(__fadd_rn(q8[0], q8[1]), __fadd_rn(q8[2], q8[3])),
                              __fadd_rn(__fadd_rn(q8[4], q8[5]), __fadd_rn(q8[6], q8[7])));
        float d2 = __fadd_rn(__fsub_rn(rrow, __fmul_rn(2.0f, dot)), w2e);
        if (d2 < bestd) { bestd = d2; besti = v; }
      }
      resc_d2f[t] = bestd; resc_ixs[t] = besti;
      __syncthreads();
      if (t == 0) {
        float bd = resc_d2f[0]; int bi = resc_ixs[0];
        for (int k = 1; k < NT; ++k)
          if (resc_d2f[k] < bd) { bd = resc_d2f[k]; bi = resc_ixs[k]; }
        idx_lds[row] = bi;
      }
      __syncthreads();
    }

    // ---- update: r -= q (exact fp32); loss += r_new^2 ----
    {
      int row = t >> 1, half = t & 1;
      int code = idx_lds[row];
      const float4* qp = (const float4*)(emb + (((size_t)stage * V + code) * D + half * 32));
      #pragma unroll
      for (int k = 0; k < 8; ++k) {
        float4 qv = qp[k];
        float* rp = &Rt[row][half * 32 + k * 4];
        float r0 = rp[0] - qv.x, r1 = rp[1] - qv.y, r2 = rp[2] - qv.z, r3 = rp[3] - qv.w;
        rp[0] = r0; rp[1] = r1; rp[2] = r2; rp[3] = r3;
        loss_acc += r0 * r0 + r1 * r1 + r2 * r2 + r3 * r3;
      }
    }
    // next stage-top __syncthreads() protects Rt reads-after-write
  } // stages

  __syncthreads();

  // ---- epilogue: quantised = latent - r_final (coalesced dword stores at out+1) ----
  for (int k = 0; k < 32; ++k) {
    int idx = t + k * NT;
    int row = idx >> 6, dd = idx & 63;
    float l = latent[row0 * D + idx];
    out[1 + row0 * D + idx] = l - Rt[row][dd];
  }

  // ---- loss reduction + atomic ----
  loss_red[t] = loss_acc;
  __syncthreads();
  for (int s = NT / 2; s > 0; s >>= 1) {
    if (t < s) loss_red[t] += loss_red[t + s];
    __syncthreads();
  }
  if (t == 0) atomicAdd(out, loss_red[0] * LOSS_SCALE);
}

extern "C" void kernel_launch(void* const* d_in, const int* in_sizes, int n_in,
                              void* d_out, int out_size, void* d_ws, size_t ws_size,
                              hipStream_t stream) {
  const float* latent = (const float*)d_in[0];
  const float* emb    = (const float*)d_in[1];
  float* out = (float*)d_out;

  unsigned short* Wfrag = (unsigned short*)d_ws;            // HQ*V*D*2 ushorts = 1 MB
  float* W2 = (float*)(Wfrag + (size_t)HQ * V * D * 2);     // HQ*V floats = 16 KB

  vq_prep<<<(HQ * V + NT - 1) / NT, NT, 0, stream>>>(emb, Wfrag, W2, out);
  vq_main<<<M_TOTAL / MR, NT, 0, stream>>>(latent, emb, Wfrag, W2, out);
}

// Round 7
// 775.335 us; speedup vs baseline: 1.0200x; 1.0200x over previous
//
#include <hip/hip_runtime.h>

// Problem constants (fixed by the reference)
#define D        64
#define V        1024
#define HQ       4
#define M_TOTAL  131072      // 32 * 4096 rows
#define MR       128         // rows per block
#define NT       256         // threads per block
#define TAU      4e-3f       // near-tie rescue threshold (bf16-split fast-path err <~6e-4)
#define LOSS_SCALE (1.25f / 8388608.0f)
#define RT_STRIDE 68         // 64 + 4 pad (keeps rows 16B-aligned)

typedef __attribute__((ext_vector_type(8))) short short8;
typedef __attribute__((ext_vector_type(4))) float f32x4;

// ---- ordered-float <-> uint transforms (ascending float == ascending uint) ----
__device__ __forceinline__ unsigned int f2ord(float f) {
  unsigned int b = __float_as_uint(f);
  return b ^ (((unsigned int)((int)b >> 31)) | 0x80000000u);
}
__device__ __forceinline__ float ord2f(unsigned int u) {
  unsigned int b = u ^ ((~((unsigned int)((int)u >> 31))) | 0x80000000u);
  return __uint_as_float(b);
}
// bf16 round-to-nearest-even
__device__ __forceinline__ unsigned short f2bf(float f) {
  unsigned int u = __float_as_uint(f);
  return (unsigned short)((u + 0x7fffu + ((u >> 16) & 1u)) >> 16);
}

// ---- prep: split codebook into bf16 hi/lo in MFMA-fragment order, w2, zero loss ----
// Fragment layout (short8 units within a stage): unit = ((ct*2+kk)*2+hl)*64 + lane,
// holding W[code=ct*16+(lane&15)][k=kk*32+(lane>>4)*8 + j], j=0..7 as bf16.
__global__ void vq_prep(const float* __restrict__ emb, unsigned short* __restrict__ Wfrag,
                        float* __restrict__ W2, float* __restrict__ out) {
  int t = blockIdx.x * NT + threadIdx.x;   // over HQ*V = 4096
  if (t == 0) out[0] = 0.0f;
  if (t >= HQ * V) return;
  int s = t >> 10, v = t & (V - 1);
  int ct = v >> 4, cl = v & 15;
  const float* e = emb + (size_t)t * D;
  float w2 = 0.0f;
  for (int k = 0; k < D; ++k) {
    float f = e[k];
    w2 += f * f;
    unsigned short hb = f2bf(f);
    float fh = __uint_as_float((unsigned int)hb << 16);
    unsigned short lb = f2bf(f - fh);
    int kk = k >> 5, q = (k >> 3) & 3, j = k & 7;
    size_t base = (((size_t)(s * 64 + ct) * 2 + kk) * 2) * 512
                + (size_t)(q * 16 + cl) * 8 + j;
    Wfrag[base]       = hb;   // hl = 0
    Wfrag[base + 512] = lb;   // hl = 1
  }
  W2[t] = w2;
}

// ---- main kernel: 128 rows/block, 4 waves, MFMA bf16-split, B direct from global ----
// __launch_bounds__(NT,2): 128 VGPRs. (NT,4) pinned 64 VGPRs -> scratch spills
// (R6: WRITE_SIZE 284->568 MB). Live set ~120 VGPRs needs the 128 budget.
__launch_bounds__(NT, 2)
__global__ void vq_main(const float* __restrict__ latent,
                        const float* __restrict__ emb,
                        const unsigned short* __restrict__ Wfrag,
                        const float* __restrict__ W2,
                        float* __restrict__ out) {
  __shared__ float Rt[MR][RT_STRIDE];   // 34.8 KB fp32 residual
  __shared__ int idx_lds[MR];
  __shared__ int n_rescue;
  __shared__ int rescue_rows[MR];
  __shared__ float resc_d2f[NT];
  __shared__ int   resc_ixs[NT];
  __shared__ float loss_red[NT];

  const int t    = threadIdx.x;
  const int lane = t & 63;
  const int w    = t >> 6;       // wave id: rows [w*32, w*32+32)
  const int cl   = lane & 15;
  const int q    = lane >> 4;
  const size_t row0 = (size_t)blockIdx.x * MR;

  if (t == 0) n_rescue = 0;

  // ---- load latent tile -> Rt (coalesced float4) ----
  {
    const float4* lg = (const float4*)(latent + row0 * D);
    #pragma unroll
    for (int k = 0; k < 8; ++k) {
      int i4 = t + k * NT;
      int row = i4 >> 4, dd = (i4 & 15) * 4;
      *(float4*)&Rt[row][dd] = lg[i4];
    }
  }

  float loss_acc = 0.0f;

  for (int stage = 0; stage < HQ; ++stage) {
    __syncthreads();           // Rt ready (initial load or previous stage's update)

    // ---- build A fragments (bf16 hi/lo) from Rt ----
    short8 Ah[2][2], Al[2][2];
    #pragma unroll
    for (int rt = 0; rt < 2; ++rt)
      #pragma unroll
      for (int kk = 0; kk < 2; ++kk) {
        const float* rp = &Rt[w * 32 + rt * 16 + cl][kk * 32 + q * 8];
        short8 h, l;
        #pragma unroll
        for (int j = 0; j < 8; ++j) {
          float f = rp[j];
          unsigned short hb = f2bf(f);
          float fh = __uint_as_float((unsigned int)hb << 16);
          h[j] = (short)hb;
          l[j] = (short)f2bf(f - fh);
        }
        Ah[rt][kk] = h; Al[rt][kk] = l;
      }

    // per-lane top-2: slot (rt,r) covers row = w*32+rt*16+q*4+r, cols ≡ cl (mod 16)
    float m1[2][4], m2[2][4]; int i1[2][4];
    #pragma unroll
    for (int rt = 0; rt < 2; ++rt)
      #pragma unroll
      for (int r = 0; r < 4; ++r) { m1[rt][r] = INFINITY; m2[rt][r] = INFINITY; i1[rt][r] = 0; }

    const short8* wb = (const short8*)(Wfrag + (size_t)stage * 131072);
    const float* w2p = W2 + stage * V;

    // ---- ct loop: 64 code-tiles, 2-deep ping-pong B prefetch, no barriers ----
    short8 B0[4], B1[4]; float w2a, w2b;
    {
      int base = lane;
      B0[0] = wb[base]; B0[1] = wb[base + 64]; B0[2] = wb[base + 128]; B0[3] = wb[base + 192];
      w2a = w2p[cl];
    }
    #pragma unroll 1
    for (int ct = 0; ct < 64; ct += 2) {
      {   // prefetch ct+1
        int base = (ct + 1) * 256 + lane;
        B1[0] = wb[base]; B1[1] = wb[base + 64]; B1[2] = wb[base + 128]; B1[3] = wb[base + 192];
        w2b = w2p[(ct + 1) * 16 + cl];
      }
      {   // compute ct with B0
        int code = ct * 16 + cl;
        #pragma unroll
        for (int rt = 0; rt < 2; ++rt) {
          f32x4 C1 = {0.f,0.f,0.f,0.f}, C2 = {0.f,0.f,0.f,0.f};
          C1 = __builtin_amdgcn_mfma_f32_16x16x32_bf16(Ah[rt][0], B0[0], C1, 0, 0, 0);
          C1 = __builtin_amdgcn_mfma_f32_16x16x32_bf16(Ah[rt][1], B0[2], C1, 0, 0, 0);
          C2 = __builtin_amdgcn_mfma_f32_16x16x32_bf16(Al[rt][0], B0[0], C2, 0, 0, 0);
          C2 = __builtin_amdgcn_mfma_f32_16x16x32_bf16(Al[rt][1], B0[2], C2, 0, 0, 0);
          C2 = __builtin_amdgcn_mfma_f32_16x16x32_bf16(Ah[rt][0], B0[1], C2, 0, 0, 0);
          C2 = __builtin_amdgcn_mfma_f32_16x16x32_bf16(Ah[rt][1], B0[3], C2, 0, 0, 0);
          #pragma unroll
          for (int r = 0; r < 4; ++r) {
            float s = fmaf(-2.0f, C1[r] + C2[r], w2a);
            m2[rt][r] = fminf(m2[rt][r], fmaxf(s, m1[rt][r]));
            bool lt = s < m1[rt][r];
            m1[rt][r] = fminf(m1[rt][r], s);
            i1[rt][r] = lt ? code : i1[rt][r];
          }
        }
      }
      {   // prefetch ct+2 (clamped dup at the tail: harmless)
        int ctn = (ct + 2 < 64) ? ct + 2 : 63;
        int base = ctn * 256 + lane;
        B0[0] = wb[base]; B0[1] = wb[base + 64]; B0[2] = wb[base + 128]; B0[3] = wb[base + 192];
        w2a = w2p[ctn * 16 + cl];
      }
      {   // compute ct+1 with B1
        int code = (ct + 1) * 16 + cl;
        #pragma unroll
        for (int rt = 0; rt < 2; ++rt) {
          f32x4 C1 = {0.f,0.f,0.f,0.f}, C2 = {0.f,0.f,0.f,0.f};
          C1 = __builtin_amdgcn_mfma_f32_16x16x32_bf16(Ah[rt][0], B1[0], C1, 0, 0, 0);
          C1 = __builtin_amdgcn_mfma_f32_16x16x32_bf16(Ah[rt][1], B1[2], C1, 0, 0, 0);
          C2 = __builtin_amdgcn_mfma_f32_16x16x32_bf16(Al[rt][0], B1[0], C2, 0, 0, 0);
          C2 = __builtin_amdgcn_mfma_f32_16x16x32_bf16(Al[rt][1], B1[2], C2, 0, 0, 0);
          C2 = __builtin_amdgcn_mfma_f32_16x16x32_bf16(Ah[rt][0], B1[1], C2, 0, 0, 0);
          C2 = __builtin_amdgcn_mfma_f32_16x16x32_bf16(Ah[rt][1], B1[3], C2, 0, 0, 0);
          #pragma unroll
          for (int r = 0; r < 4; ++r) {
            float s = fmaf(-2.0f, C1[r] + C2[r], w2b);
            m2[rt][r] = fminf(m2[rt][r], fmaxf(s, m1[rt][r]));
            bool lt = s < m1[rt][r];
            m1[rt][r] = fminf(m1[rt][r], s);
            i1[rt][r] = lt ? code : i1[rt][r];
          }
        }
      }
    } // ct

    // ---- 16-lane butterfly top-2 reduction ----
    #pragma unroll
    for (int rt = 0; rt < 2; ++rt)
      #pragma unroll
      for (int r = 0; r < 4; ++r) {
        unsigned int phi = f2ord(m1[rt][r]);
        unsigned int plo = (unsigned int)i1[rt][r];
        unsigned int s2  = f2ord(m2[rt][r]);
        #pragma unroll
        for (int mask = 1; mask <= 8; mask <<= 1) {
          unsigned int ohi = (unsigned int)__shfl_xor((int)phi, mask, 16);
          unsigned int olo = (unsigned int)__shfl_xor((int)plo, mask, 16);
          unsigned int os2 = (unsigned int)__shfl_xor((int)s2, mask, 16);
          unsigned long long p  = ((unsigned long long)phi << 32) | plo;
          unsigned long long po = ((unsigned long long)ohi << 32) | olo;
          unsigned int hmax = phi > ohi ? phi : ohi;
          s2 = s2 < os2 ? s2 : os2;
          s2 = s2 < hmax ? s2 : hmax;
          unsigned long long pm = p < po ? p : po;   // ties -> smaller idx (first index)
          phi = (unsigned int)(pm >> 32); plo = (unsigned int)pm;
        }
        if (cl == 0) {
          int row = w * 32 + rt * 16 + q * 4 + r;
          idx_lds[row] = (int)plo;
          float gap = ord2f(s2) - ord2f(phi);
          if (gap < TAU) {
            int slot = atomicAdd(&n_rescue, 1);
            rescue_rows[slot] = row;
          }
        }
      }
    __syncthreads();   // idx_lds + rescue flags visible
    int nres = n_rescue;
    __syncthreads();   // all reads of n_rescue done
    if (t == 0) n_rescue = 0;  // for next stage; ordered before next adds by stage-top barrier

    // ---- near-tie rescue: bit-exact numpy-reference emulation (verified R4/R5) ----
    for (int rr_i = 0; rr_i < nres; ++rr_i) {
      int row = rescue_rows[rr_i];
      float p8[8];
      #pragma unroll
      for (int j = 0; j < 8; ++j) p8[j] = __fmul_rn(Rt[row][j], Rt[row][j]);
      #pragma unroll
      for (int i = 1; i < 8; ++i)
        #pragma unroll
        for (int j = 0; j < 8; ++j)
          p8[j] = __fadd_rn(p8[j], __fmul_rn(Rt[row][8 * i + j], Rt[row][8 * i + j]));
      float rrow = __fadd_rn(__fadd_rn(__fadd_rn(p8[0], p8[1]), __fadd_rn(p8[2], p8[3])),
                             __fadd_rn(__fadd_rn(p8[4], p8[5]), __fadd_rn(p8[6], p8[7])));
      const float* eb = emb + (size_t)stage * V * D;
      float bestd = INFINITY; int besti = 0;
      #pragma unroll
      for (int c = 0; c < 4; ++c) {
        int v = t * 4 + c;
        const float* wv = eb + (size_t)v * D;
        float dot = 0.0f;
        #pragma unroll
        for (int d = 0; d < D; ++d) dot = __fmaf_rn(Rt[row][d], wv[d], dot);
        float q8[8];
        #pragma unroll
        for (int j = 0; j < 8; ++j) q8[j] = __fmul_rn(wv[j], wv[j]);
        #pragma unroll
        for (int i = 1; i < 8; ++i)
          #pragma unroll
          for (int j = 0; j < 8; ++j)
            q8[j] = __fadd_rn(q8[j], __fmul_rn(wv[8 * i + j], wv[8 * i + j]));
        float w2e = __fadd_rn(__fadd_rn(__fadd_rn(q8[0], q8[1]), __fadd_rn(q8[2], q8[3])),
                              __fadd_rn(__fadd_rn(q8[4], q8[5]), __fadd_rn(q8[6], q8[7])));
        float d2 = __fadd_rn(__fsub_rn(rrow, __fmul_rn(2.0f, dot)), w2e);
        if (d2 < bestd) { bestd = d2; besti = v; }
      }
      resc_d2f[t] = bestd; resc_ixs[t] = besti;
      __syncthreads();
      if (t == 0) {
        float bd = resc_d2f[0]; int bi = resc_ixs[0];
        for (int k = 1; k < NT; ++k)
          if (resc_d2f[k] < bd) { bd = resc_d2f[k]; bi = resc_ixs[k]; }
        idx_lds[row] = bi;
      }
      __syncthreads();
    }

    // ---- update: r -= q (exact fp32); loss += r_new^2 ----
    {
      int row = t >> 1, half = t & 1;
      int code = idx_lds[row];
      const float4* qp = (const float4*)(emb + (((size_t)stage * V + code) * D + half * 32));
      #pragma unroll
      for (int k = 0; k < 8; ++k) {
        float4 qv = qp[k];
        float* rp = &Rt[row][half * 32 + k * 4];
        float r0 = rp[0] - qv.x, r1 = rp[1] - qv.y, r2 = rp[2] - qv.z, r3 = rp[3] - qv.w;
        rp[0] = r0; rp[1] = r1; rp[2] = r2; rp[3] = r3;
        loss_acc += r0 * r0 + r1 * r1 + r2 * r2 + r3 * r3;
      }
    }
    // next stage-top __syncthreads() protects Rt reads-after-write
  } // stages

  __syncthreads();

  // ---- epilogue: quantised = latent - r_final (coalesced dword stores at out+1) ----
  for (int k = 0; k < 32; ++k) {
    int idx = t + k * NT;
    int row = idx >> 6, dd = idx & 63;
    float l = latent[row0 * D + idx];
    out[1 + row0 * D + idx] = l - Rt[row][dd];
  }

  // ---- loss reduction + atomic ----
  loss_red[t] = loss_acc;
  __syncthreads();
  for (int s = NT / 2; s > 0; s >>= 1) {
    if (t < s) loss_red[t] += loss_red[t + s];
    __syncthreads();
  }
  if (t == 0) atomicAdd(out, loss_red[0] * LOSS_SCALE);
}

extern "C" void kernel_launch(void* const* d_in, const int* in_sizes, int n_in,
                              void* d_out, int out_size, void* d_ws, size_t ws_size,
                              hipStream_t stream) {
  const float* latent = (const float*)d_in[0];
  const float* emb    = (const float*)d_in[1];
  float* out = (float*)d_out;

  unsigned short* Wfrag = (unsigned short*)d_ws;            // HQ*V*D*2 ushorts = 1 MB
  float* W2 = (float*)(Wfrag + (size_t)HQ * V * D * 2);     // HQ*V floats = 16 KB

  vq_prep<<<(HQ * V + NT - 1) / NT, NT, 0, stream>>>(emb, Wfrag, W2, out);
  vq_main<<<M_TOTAL / MR, NT, 0, stream>>>(latent, emb, Wfrag, W2, out);
}

// Round 8
// 754.270 us; speedup vs baseline: 1.0485x; 1.0279x over previous
//
#include <hip/hip_runtime.h>

// Problem constants (fixed by the reference)
#define D        64
#define V        1024
#define HQ       4
#define M_TOTAL  131072      // 32 * 4096 rows
#define MR       128         // rows per block
#define NT       256         // threads per block
#define TAU      4e-3f       // near-tie rescue threshold (bf16-split fast-path err <~6e-4)
#define LOSS_SCALE (1.25f / 8388608.0f)
#define RT_STRIDE 68         // 64 + 4 pad (keeps rows 16B-aligned)

typedef __attribute__((ext_vector_type(8))) short short8;
typedef __attribute__((ext_vector_type(4))) float f32x4;

// ---- ordered-float <-> uint transforms (ascending float == ascending uint) ----
__device__ __forceinline__ unsigned int f2ord(float f) {
  unsigned int b = __float_as_uint(f);
  return b ^ (((unsigned int)((int)b >> 31)) | 0x80000000u);
}
__device__ __forceinline__ float ord2f(unsigned int u) {
  unsigned int b = u ^ ((~((unsigned int)((int)u >> 31))) | 0x80000000u);
  return __uint_as_float(b);
}
// bf16 round-to-nearest-even
__device__ __forceinline__ unsigned short f2bf(float f) {
  unsigned int u = __float_as_uint(f);
  return (unsigned short)((u + 0x7fffu + ((u >> 16) & 1u)) >> 16);
}

// ---- prep: split codebook into bf16 hi/lo in MFMA-fragment order, w2, zero loss ----
// Fragment layout (short8 units within a stage): unit = ((ct*2+kk)*2+hl)*64 + lane,
// holding W[code=ct*16+(lane&15)][k=kk*32+(lane>>4)*8 + j], j=0..7 as bf16.
__global__ void vq_prep(const float* __restrict__ emb, unsigned short* __restrict__ Wfrag,
                        float* __restrict__ W2, float* __restrict__ out) {
  int t = blockIdx.x * NT + threadIdx.x;   // over HQ*V = 4096
  if (t == 0) out[0] = 0.0f;
  if (t >= HQ * V) return;
  int s = t >> 10, v = t & (V - 1);
  int ct = v >> 4, cl = v & 15;
  const float* e = emb + (size_t)t * D;
  float w2 = 0.0f;
  for (int k = 0; k < D; ++k) {
    float f = e[k];
    w2 += f * f;
    unsigned short hb = f2bf(f);
    float fh = __uint_as_float((unsigned int)hb << 16);
    unsigned short lb = f2bf(f - fh);
    int kk = k >> 5, q = (k >> 3) & 3, j = k & 7;
    size_t base = (((size_t)(s * 64 + ct) * 2 + kk) * 2) * 512
                + (size_t)(q * 16 + cl) * 8 + j;
    Wfrag[base]       = hb;   // hl = 0
    Wfrag[base + 512] = lb;   // hl = 1
  }
  W2[t] = w2;
}

// ---- main kernel: 128 rows/block, 4 waves, MFMA bf16-split, B direct from L2 ----
// Register budget is the whole game (R6/R7 post-mortem: spill traffic ~450 MB/dispatch
// was the stall). Live set kept < 128: single B buffer (no ping-pong; 4 resident
// waves/SIMD cover the L2 latency), sequential rt sharing one C1/C2 pair.
__launch_bounds__(NT, 2)
__global__ void vq_main(const float* __restrict__ latent,
                        const float* __restrict__ emb,
                        const unsigned short* __restrict__ Wfrag,
                        const float* __restrict__ W2,
                        float* __restrict__ out) {
  __shared__ float Rt[MR][RT_STRIDE];   // 34.8 KB fp32 residual
  __shared__ int idx_lds[MR];
  __shared__ int n_rescue;
  __shared__ int rescue_rows[MR];
  __shared__ float resc_d2f[NT];
  __shared__ int   resc_ixs[NT];
  __shared__ float loss_red[NT];

  const int t    = threadIdx.x;
  const int lane = t & 63;
  const int w    = t >> 6;       // wave id: rows [w*32, w*32+32)
  const int cl   = lane & 15;
  const int q    = lane >> 4;
  const size_t row0 = (size_t)blockIdx.x * MR;

  if (t == 0) n_rescue = 0;

  // ---- load latent tile -> Rt (coalesced float4) ----
  {
    const float4* lg = (const float4*)(latent + row0 * D);
    #pragma unroll
    for (int k = 0; k < 8; ++k) {
      int i4 = t + k * NT;
      int row = i4 >> 4, dd = (i4 & 15) * 4;
      *(float4*)&Rt[row][dd] = lg[i4];
    }
  }

  float loss_acc = 0.0f;

  for (int stage = 0; stage < HQ; ++stage) {
    __syncthreads();           // Rt ready (initial load or previous stage's update)

    // ---- build A fragments (bf16 hi/lo) from Rt ----
    short8 Ah[2][2], Al[2][2];
    #pragma unroll
    for (int rt = 0; rt < 2; ++rt)
      #pragma unroll
      for (int kk = 0; kk < 2; ++kk) {
        const float* rp = &Rt[w * 32 + rt * 16 + cl][kk * 32 + q * 8];
        short8 h, l;
        #pragma unroll
        for (int j = 0; j < 8; ++j) {
          float f = rp[j];
          unsigned short hb = f2bf(f);
          float fh = __uint_as_float((unsigned int)hb << 16);
          h[j] = (short)hb;
          l[j] = (short)f2bf(f - fh);
        }
        Ah[rt][kk] = h; Al[rt][kk] = l;
      }

    // per-lane top-2: slot (rt,r) covers row = w*32+rt*16+q*4+r, cols ≡ cl (mod 16)
    float m1[2][4], m2[2][4]; int i1[2][4];
    #pragma unroll
    for (int rt = 0; rt < 2; ++rt)
      #pragma unroll
      for (int r = 0; r < 4; ++r) { m1[rt][r] = INFINITY; m2[rt][r] = INFINITY; i1[rt][r] = 0; }

    const short8* wb = (const short8*)(Wfrag + (size_t)stage * 131072);
    const float* w2p = W2 + stage * V;

    // ---- ct loop: 64 code-tiles; single B buffer, no barriers ----
    #pragma unroll 1
    for (int ct = 0; ct < 64; ++ct) {
      int base = ct * 256 + lane;
      short8 B0 = wb[base];
      short8 B1 = wb[base + 64];
      short8 B2 = wb[base + 128];
      short8 B3 = wb[base + 192];
      float w2v = w2p[ct * 16 + cl];
      int code = ct * 16 + cl;
      #pragma unroll
      for (int rt = 0; rt < 2; ++rt) {
        f32x4 C1 = {0.f,0.f,0.f,0.f}, C2 = {0.f,0.f,0.f,0.f};
        C1 = __builtin_amdgcn_mfma_f32_16x16x32_bf16(Ah[rt][0], B0, C1, 0, 0, 0);
        C1 = __builtin_amdgcn_mfma_f32_16x16x32_bf16(Ah[rt][1], B2, C1, 0, 0, 0);
        C2 = __builtin_amdgcn_mfma_f32_16x16x32_bf16(Al[rt][0], B0, C2, 0, 0, 0);
        C2 = __builtin_amdgcn_mfma_f32_16x16x32_bf16(Al[rt][1], B2, C2, 0, 0, 0);
        C2 = __builtin_amdgcn_mfma_f32_16x16x32_bf16(Ah[rt][0], B1, C2, 0, 0, 0);
        C2 = __builtin_amdgcn_mfma_f32_16x16x32_bf16(Ah[rt][1], B3, C2, 0, 0, 0);
        #pragma unroll
        for (int r = 0; r < 4; ++r) {
          float s = fmaf(-2.0f, C1[r] + C2[r], w2v);
          m2[rt][r] = fminf(m2[rt][r], fmaxf(s, m1[rt][r]));
          bool lt = s < m1[rt][r];
          m1[rt][r] = fminf(m1[rt][r], s);
          i1[rt][r] = lt ? code : i1[rt][r];
        }
      }
    } // ct

    // ---- 16-lane butterfly top-2 reduction ----
    #pragma unroll
    for (int rt = 0; rt < 2; ++rt)
      #pragma unroll
      for (int r = 0; r < 4; ++r) {
        unsigned int phi = f2ord(m1[rt][r]);
        unsigned int plo = (unsigned int)i1[rt][r];
        unsigned int s2  = f2ord(m2[rt][r]);
        #pragma unroll
        for (int mask = 1; mask <= 8; mask <<= 1) {
          unsigned int ohi = (unsigned int)__shfl_xor((int)phi, mask, 16);
          unsigned int olo = (unsigned int)__shfl_xor((int)plo, mask, 16);
          unsigned int os2 = (unsigned int)__shfl_xor((int)s2, mask, 16);
          unsigned long long p  = ((unsigned long long)phi << 32) | plo;
          unsigned long long po = ((unsigned long long)ohi << 32) | olo;
          unsigned int hmax = phi > ohi ? phi : ohi;
          s2 = s2 < os2 ? s2 : os2;
          s2 = s2 < hmax ? s2 : hmax;
          unsigned long long pm = p < po ? p : po;   // ties -> smaller idx (first index)
          phi = (unsigned int)(pm >> 32); plo = (unsigned int)pm;
        }
        if (cl == 0) {
          int row = w * 32 + rt * 16 + q * 4 + r;
          idx_lds[row] = (int)plo;
          float gap = ord2f(s2) - ord2f(phi);
          if (gap < TAU) {
            int slot = atomicAdd(&n_rescue, 1);
            rescue_rows[slot] = row;
          }
        }
      }
    __syncthreads();   // idx_lds + rescue flags visible
    int nres = n_rescue;
    __syncthreads();   // all reads of n_rescue done
    if (t == 0) n_rescue = 0;  // for next stage; ordered by the following barriers

    // ---- near-tie rescue: bit-exact numpy-reference emulation (verified R4/R5) ----
    for (int rr_i = 0; rr_i < nres; ++rr_i) {
      int row = rescue_rows[rr_i];
      float p8[8];
      #pragma unroll
      for (int j = 0; j < 8; ++j) p8[j] = __fmul_rn(Rt[row][j], Rt[row][j]);
      #pragma unroll
      for (int i = 1; i < 8; ++i)
        #pragma unroll
        for (int j = 0; j < 8; ++j)
          p8[j] = __fadd_rn(p8[j], __fmul_rn(Rt[row][8 * i + j], Rt[row][8 * i + j]));
      float rrow = __fadd_rn(__fadd_rn(__fadd_rn(p8[0], p8[1]), __fadd_rn(p8[2], p8[3])),
                             __fadd_rn(__fadd_rn(p8[4], p8[5]), __fadd_rn(p8[6], p8[7])));
      const float* eb = emb + (size_t)stage * V * D;
      float bestd = INFINITY; int besti = 0;
      #pragma unroll
      for (int c = 0; c < 4; ++c) {
        int v = t * 4 + c;
        const float* wv = eb + (size_t)v * D;
        float dot = 0.0f;
        #pragma unroll
        for (int d = 0; d < D; ++d) dot = __fmaf_rn(Rt[row][d], wv[d], dot);
        float q8[8];
        #pragma unroll
        for (int j = 0; j < 8; ++j) q8[j] = __fmul_rn(wv[j], wv[j]);
        #pragma unroll
        for (int i = 1; i < 8; ++i)
          #pragma unroll
          for (int j = 0; j < 8; ++j)
            q8[j] = __fadd_rn(q8[j], __fmul_rn(wv[8 * i + j], wv[8 * i + j]));
        float w2e = __fadd_rn(__fadd_rn(__fadd_rn(q8[0], q8[1]), __fadd_rn(q8[2], q8[3])),
                              __fadd_rn(__fadd_rn(q8[4], q8[5]), __fadd_rn(q8[6], q8[7])));
        float d2 = __fadd_rn(__fsub_rn(rrow, __fmul_rn(2.0f, dot)), w2e);
        if (d2 < bestd) { bestd = d2; besti = v; }
      }
      resc_d2f[t] = bestd; resc_ixs[t] = besti;
      __syncthreads();
      if (t == 0) {
        float bd = resc_d2f[0]; int bi = resc_ixs[0];
        for (int k = 1; k < NT; ++k)
          if (resc_d2f[k] < bd) { bd = resc_d2f[k]; bi = resc_ixs[k]; }
        idx_lds[row] = bi;
      }
      __syncthreads();
    }

    // ---- update: r -= q (exact fp32); loss += r_new^2 ----
    {
      int row = t >> 1, half = t & 1;
      int code = idx_lds[row];
      const float4* qp = (const float4*)(emb + (((size_t)stage * V + code) * D + half * 32));
      #pragma unroll
      for (int k = 0; k < 8; ++k) {
        float4 qv = qp[k];
        float* rp = &Rt[row][half * 32 + k * 4];
        float r0 = rp[0] - qv.x, r1 = rp[1] - qv.y, r2 = rp[2] - qv.z, r3 = rp[3] - qv.w;
        rp[0] = r0; rp[1] = r1; rp[2] = r2; rp[3] = r3;
        loss_acc += r0 * r0 + r1 * r1 + r2 * r2 + r3 * r3;
      }
    }
    // next stage-top __syncthreads() protects Rt reads-after-write
  } // stages

  __syncthreads();

  // ---- epilogue: quantised = latent - r_final (coalesced dword stores at out+1) ----
  for (int k = 0; k < 32; ++k) {
    int idx = t + k * NT;
    int row = idx >> 6, dd = idx & 63;
    float l = latent[row0 * D + idx];
    out[1 + row0 * D + idx] = l - Rt[row][dd];
  }

  // ---- loss reduction + atomic ----
  loss_red[t] = loss_acc;
  __syncthreads();
  for (int s = NT / 2; s > 0; s >>= 1) {
    if (t < s) loss_red[t] += loss_red[t + s];
    __syncthreads();
  }
  if (t == 0) atomicAdd(out, loss_red[0] * LOSS_SCALE);
}

extern "C" void kernel_launch(void* const* d_in, const int* in_sizes, int n_in,
                              void* d_out, int out_size, void* d_ws, size_t ws_size,
                              hipStream_t stream) {
  const float* latent = (const float*)d_in[0];
  const float* emb    = (const float*)d_in[1];
  float* out = (float*)d_out;

  unsigned short* Wfrag = (unsigned short*)d_ws;            // HQ*V*D*2 ushorts = 1 MB
  float* W2 = (float*)(Wfrag + (size_t)HQ * V * D * 2);     // HQ*V floats = 16 KB

  vq_prep<<<(HQ * V + NT - 1) / NT, NT, 0, stream>>>(emb, Wfrag, W2, out);
  vq_main<<<M_TOTAL / MR, NT, 0, stream>>>(latent, emb, Wfrag, W2, out);
}

// Round 9
// 668.616 us; speedup vs baseline: 1.1828x; 1.1281x over previous
//
#include <hip/hip_runtime.h>

// Problem constants (fixed by the reference)
#define D        64
#define V        1024
#define HQ       4
#define M_TOTAL  131072      // 32 * 4096 rows
#define MR       128         // rows per block
#define NT       256         // threads per block
#define TAU      4e-3f       // near-tie rescue threshold (bf16-split fast-path err <~6e-4)
#define LOSS_SCALE (1.25f / 8388608.0f)
#define RT_STRIDE 68         // 64 + 4 pad (keeps rows 16B-aligned)

typedef __attribute__((ext_vector_type(8))) short short8;
typedef __attribute__((ext_vector_type(4))) float f32x4;

// ---- ordered-float <-> uint transforms (ascending float == ascending uint) ----
__device__ __forceinline__ unsigned int f2ord(float f) {
  unsigned int b = __float_as_uint(f);
  return b ^ (((unsigned int)((int)b >> 31)) | 0x80000000u);
}
__device__ __forceinline__ float ord2f(unsigned int u) {
  unsigned int b = u ^ ((~((unsigned int)((int)u >> 31))) | 0x80000000u);
  return __uint_as_float(b);
}
// bf16 round-to-nearest-even
__device__ __forceinline__ unsigned short f2bf(float f) {
  unsigned int u = __float_as_uint(f);
  return (unsigned short)((u + 0x7fffu + ((u >> 16) & 1u)) >> 16);
}

// ---- prep: split codebook into bf16 hi/lo in MFMA-fragment order, w2, zero loss ----
// Fragment layout (short8 units within a stage): unit = ((ct*2+kk)*2+hl)*64 + lane,
// holding W[code=ct*16+(lane&15)][k=kk*32+(lane>>4)*8 + j], j=0..7 as bf16.
__global__ void vq_prep(const float* __restrict__ emb, unsigned short* __restrict__ Wfrag,
                        float* __restrict__ W2, float* __restrict__ out) {
  int t = blockIdx.x * NT + threadIdx.x;   // over HQ*V = 4096
  if (t == 0) out[0] = 0.0f;
  if (t >= HQ * V) return;
  int s = t >> 10, v = t & (V - 1);
  int ct = v >> 4, cl = v & 15;
  const float* e = emb + (size_t)t * D;
  float w2 = 0.0f;
  for (int k = 0; k < D; ++k) {
    float f = e[k];
    w2 += f * f;
    unsigned short hb = f2bf(f);
    float fh = __uint_as_float((unsigned int)hb << 16);
    unsigned short lb = f2bf(f - fh);
    int kk = k >> 5, q = (k >> 3) & 3, j = k & 7;
    size_t base = (((size_t)(s * 64 + ct) * 2 + kk) * 2) * 512
                + (size_t)(q * 16 + cl) * 8 + j;
    Wfrag[base]       = hb;   // hl = 0
    Wfrag[base + 512] = lb;   // hl = 1
  }
  W2[t] = w2;
}

// ---- main kernel: 128 rows/block, 4 waves, MFMA bf16-split, B direct from L2 ----
// R8 post-mortem: ~260 MB/dispatch of scratch writes (WRITE_SIZE 294 vs 34 MB of
// output) across three structures -> allocator spilling under the 128-arch-VGPR cap
// implied by __launch_bounds__(NT,2)'s unified budget. (NT,1) gives the full
// 512-reg unified file; hot-loop live set ~95 regs -> no scratch possible.
__launch_bounds__(NT, 1)
__global__ void vq_main(const float* __restrict__ latent,
                        const float* __restrict__ emb,
                        const unsigned short* __restrict__ Wfrag,
                        const float* __restrict__ W2,
                        float* __restrict__ out) {
  __shared__ float Rt[MR][RT_STRIDE];   // 34.8 KB fp32 residual
  __shared__ int idx_lds[MR];
  __shared__ int n_rescue;
  __shared__ int rescue_rows[MR];
  __shared__ unsigned long long resc_pack[4];   // per-wave rescue winners
  __shared__ float loss_red[NT];

  const int t    = threadIdx.x;
  const int lane = t & 63;
  const int w    = t >> 6;       // wave id: rows [w*32, w*32+32)
  const int cl   = lane & 15;
  const int q    = lane >> 4;
  const size_t row0 = (size_t)blockIdx.x * MR;

  if (t == 0) n_rescue = 0;

  // ---- load latent tile -> Rt (coalesced float4) ----
  {
    const float4* lg = (const float4*)(latent + row0 * D);
    #pragma unroll
    for (int k = 0; k < 8; ++k) {
      int i4 = t + k * NT;
      int row = i4 >> 4, dd = (i4 & 15) * 4;
      *(float4*)&Rt[row][dd] = lg[i4];
    }
  }

  float loss_acc = 0.0f;

  for (int stage = 0; stage < HQ; ++stage) {
    __syncthreads();           // Rt ready (initial load or previous stage's update)

    // ---- build A fragments (bf16 hi/lo) from Rt ----
    short8 Ah[2][2], Al[2][2];
    #pragma unroll
    for (int rt = 0; rt < 2; ++rt)
      #pragma unroll
      for (int kk = 0; kk < 2; ++kk) {
        const float* rp = &Rt[w * 32 + rt * 16 + cl][kk * 32 + q * 8];
        short8 h, l;
        #pragma unroll
        for (int j = 0; j < 8; ++j) {
          float f = rp[j];
          unsigned short hb = f2bf(f);
          float fh = __uint_as_float((unsigned int)hb << 16);
          h[j] = (short)hb;
          l[j] = (short)f2bf(f - fh);
        }
        Ah[rt][kk] = h; Al[rt][kk] = l;
      }

    // per-lane top-2: slot (rt,r) covers row = w*32+rt*16+q*4+r, cols ≡ cl (mod 16)
    float m1[2][4], m2[2][4]; int i1[2][4];
    #pragma unroll
    for (int rt = 0; rt < 2; ++rt)
      #pragma unroll
      for (int r = 0; r < 4; ++r) { m1[rt][r] = INFINITY; m2[rt][r] = INFINITY; i1[rt][r] = 0; }

    const short8* wb = (const short8*)(Wfrag + (size_t)stage * 131072);
    const float* w2p = W2 + stage * V;

    // ---- ct loop: 64 code-tiles; single B buffer, no barriers ----
    #pragma unroll 1
    for (int ct = 0; ct < 64; ++ct) {
      int base = ct * 256 + lane;
      short8 B0 = wb[base];
      short8 B1 = wb[base + 64];
      short8 B2 = wb[base + 128];
      short8 B3 = wb[base + 192];
      float w2v = w2p[ct * 16 + cl];
      int code = ct * 16 + cl;
      #pragma unroll
      for (int rt = 0; rt < 2; ++rt) {
        f32x4 C1 = {0.f,0.f,0.f,0.f}, C2 = {0.f,0.f,0.f,0.f};
        C1 = __builtin_amdgcn_mfma_f32_16x16x32_bf16(Ah[rt][0], B0, C1, 0, 0, 0);
        C1 = __builtin_amdgcn_mfma_f32_16x16x32_bf16(Ah[rt][1], B2, C1, 0, 0, 0);
        C2 = __builtin_amdgcn_mfma_f32_16x16x32_bf16(Al[rt][0], B0, C2, 0, 0, 0);
        C2 = __builtin_amdgcn_mfma_f32_16x16x32_bf16(Al[rt][1], B2, C2, 0, 0, 0);
        C2 = __builtin_amdgcn_mfma_f32_16x16x32_bf16(Ah[rt][0], B1, C2, 0, 0, 0);
        C2 = __builtin_amdgcn_mfma_f32_16x16x32_bf16(Ah[rt][1], B3, C2, 0, 0, 0);
        #pragma unroll
        for (int r = 0; r < 4; ++r) {
          float s = fmaf(-2.0f, C1[r] + C2[r], w2v);
          m2[rt][r] = fminf(m2[rt][r], fmaxf(s, m1[rt][r]));
          bool lt = s < m1[rt][r];
          m1[rt][r] = fminf(m1[rt][r], s);
          i1[rt][r] = lt ? code : i1[rt][r];
        }
      }
    } // ct

    // ---- 16-lane butterfly top-2 reduction ----
    #pragma unroll
    for (int rt = 0; rt < 2; ++rt)
      #pragma unroll
      for (int r = 0; r < 4; ++r) {
        unsigned int phi = f2ord(m1[rt][r]);
        unsigned int plo = (unsigned int)i1[rt][r];
        unsigned int s2  = f2ord(m2[rt][r]);
        #pragma unroll
        for (int mask = 1; mask <= 8; mask <<= 1) {
          unsigned int ohi = (unsigned int)__shfl_xor((int)phi, mask, 16);
          unsigned int olo = (unsigned int)__shfl_xor((int)plo, mask, 16);
          unsigned int os2 = (unsigned int)__shfl_xor((int)s2, mask, 16);
          unsigned long long p  = ((unsigned long long)phi << 32) | plo;
          unsigned long long po = ((unsigned long long)ohi << 32) | olo;
          unsigned int hmax = phi > ohi ? phi : ohi;
          s2 = s2 < os2 ? s2 : os2;
          s2 = s2 < hmax ? s2 : hmax;
          unsigned long long pm = p < po ? p : po;   // ties -> smaller idx (first index)
          phi = (unsigned int)(pm >> 32); plo = (unsigned int)pm;
        }
        if (cl == 0) {
          int row = w * 32 + rt * 16 + q * 4 + r;
          idx_lds[row] = (int)plo;
          float gap = ord2f(s2) - ord2f(phi);
          if (gap < TAU) {
            int slot = atomicAdd(&n_rescue, 1);
            rescue_rows[slot] = row;
          }
        }
      }
    __syncthreads();   // idx_lds + rescue flags visible
    int nres = n_rescue;
    __syncthreads();   // all reads of n_rescue done
    if (t == 0) n_rescue = 0;  // for next stage; ordered by the following barriers

    // ---- near-tie rescue: bit-exact numpy-reference emulation (verified R4/R5) ----
    for (int rr_i = 0; rr_i < nres; ++rr_i) {
      int row = rescue_rows[rr_i];
      float p8[8];
      #pragma unroll
      for (int j = 0; j < 8; ++j) p8[j] = __fmul_rn(Rt[row][j], Rt[row][j]);
      #pragma unroll
      for (int i = 1; i < 8; ++i)
        #pragma unroll
        for (int j = 0; j < 8; ++j)
          p8[j] = __fadd_rn(p8[j], __fmul_rn(Rt[row][8 * i + j], Rt[row][8 * i + j]));
      float rrow = __fadd_rn(__fadd_rn(__fadd_rn(p8[0], p8[1]), __fadd_rn(p8[2], p8[3])),
                             __fadd_rn(__fadd_rn(p8[4], p8[5]), __fadd_rn(p8[6], p8[7])));
      const float* eb = emb + (size_t)stage * V * D;
      float bestd = INFINITY; int besti = 0;
      #pragma unroll
      for (int c = 0; c < 4; ++c) {
        int v = t * 4 + c;
        const float* wv = eb + (size_t)v * D;
        float dot = 0.0f;
        #pragma unroll
        for (int d = 0; d < D; ++d) dot = __fmaf_rn(Rt[row][d], wv[d], dot);
        float q8[8];
        #pragma unroll
        for (int j = 0; j < 8; ++j) q8[j] = __fmul_rn(wv[j], wv[j]);
        #pragma unroll
        for (int i = 1; i < 8; ++i)
          #pragma unroll
          for (int j = 0; j < 8; ++j)
            q8[j] = __fadd_rn(q8[j], __fmul_rn(wv[8 * i + j], wv[8 * i + j]));
        float w2e = __fadd_rn(__fadd_rn(__fadd_rn(q8[0], q8[1]), __fadd_rn(q8[2], q8[3])),
                              __fadd_rn(__fadd_rn(q8[4], q8[5]), __fadd_rn(q8[6], q8[7])));
        float d2 = __fadd_rn(__fsub_rn(rrow, __fmul_rn(2.0f, dot)), w2e);
        if (d2 < bestd) { bestd = d2; besti = v; }
      }
      // parallel argmin: packed (ord(d2)<<32 | v) u64 min == min d2, first-index ties
      unsigned long long pk = ((unsigned long long)f2ord(bestd) << 32) | (unsigned int)besti;
      #pragma unroll
      for (int mask = 1; mask <= 32; mask <<= 1) {
        int lo = (int)(unsigned int)pk, hi = (int)(unsigned int)(pk >> 32);
        int olo = __shfl_xor(lo, mask, 64), ohi = __shfl_xor(hi, mask, 64);
        unsigned long long po = ((unsigned long long)(unsigned int)ohi << 32) | (unsigned int)olo;
        pk = po < pk ? po : pk;
      }
      if (lane == 0) resc_pack[w] = pk;
      __syncthreads();
      if (t == 0) {
        unsigned long long b = resc_pack[0];
        if (resc_pack[1] < b) b = resc_pack[1];
        if (resc_pack[2] < b) b = resc_pack[2];
        if (resc_pack[3] < b) b = resc_pack[3];
        idx_lds[row] = (int)(unsigned int)b;
      }
      __syncthreads();
    }

    // ---- update: r -= q (exact fp32); loss += r_new^2 ----
    {
      int row = t >> 1, half = t & 1;
      int code = idx_lds[row];
      const float4* qp = (const float4*)(emb + (((size_t)stage * V + code) * D + half * 32));
      #pragma unroll
      for (int k = 0; k < 8; ++k) {
        float4 qv = qp[k];
        float* rp = &Rt[row][half * 32 + k * 4];
        float r0 = rp[0] - qv.x, r1 = rp[1] - qv.y, r2 = rp[2] - qv.z, r3 = rp[3] - qv.w;
        rp[0] = r0; rp[1] = r1; rp[2] = r2; rp[3] = r3;
        loss_acc += r0 * r0 + r1 * r1 + r2 * r2 + r3 * r3;
      }
    }
    // next stage-top __syncthreads() protects Rt reads-after-write
  } // stages

  __syncthreads();

  // ---- epilogue: quantised = latent - r_final (nontemporal dword stores at out+1) ----
  for (int k = 0; k < 32; ++k) {
    int idx = t + k * NT;
    int row = idx >> 6, dd = idx & 63;
    float l = latent[row0 * D + idx];
    __builtin_nontemporal_store(l - Rt[row][dd], &out[1 + row0 * D + idx]);
  }

  // ---- loss reduction + atomic ----
  loss_red[t] = loss_acc;
  __syncthreads();
  for (int s = NT / 2; s > 0; s >>= 1) {
    if (t < s) loss_red[t] += loss_red[t + s];
    __syncthreads();
  }
  if (t == 0) atomicAdd(out, loss_red[0] * LOSS_SCALE);
}

extern "C" void kernel_launch(void* const* d_in, const int* in_sizes, int n_in,
                              void* d_out, int out_size, void* d_ws, size_t ws_size,
                              hipStream_t stream) {
  const float* latent = (const float*)d_in[0];
  const float* emb    = (const float*)d_in[1];
  float* out = (float*)d_out;

  unsigned short* Wfrag = (unsigned short*)d_ws;            // HQ*V*D*2 ushorts = 1 MB
  float* W2 = (float*)(Wfrag + (size_t)HQ * V * D * 2);     // HQ*V floats = 16 KB

  vq_prep<<<(HQ * V + NT - 1) / NT, NT, 0, stream>>>(emb, Wfrag, W2, out);
  vq_main<<<M_TOTAL / MR, NT, 0, stream>>>(latent, emb, Wfrag, W2, out);
}

// Round 10
// 518.319 us; speedup vs baseline: 1.5258x; 1.2900x over previous
//
#include <hip/hip_runtime.h>

// Problem constants (fixed by the reference)
#define D        64
#define V        1024
#define HQ       4
#define M_TOTAL  131072      // 32 * 4096 rows
#define MR       256         // rows per block (4 waves x 64 rows/wave)
#define NT       256         // threads per block
#define TAU      4e-3f       // near-tie rescue threshold (bf16-split fast-path err <~6e-4)
#define LOSS_SCALE (1.25f / 8388608.0f)
#define RT_STRIDE 68         // 64 + 4 pad (keeps rows 16B-aligned)

typedef __attribute__((ext_vector_type(8))) short short8;
typedef __attribute__((ext_vector_type(4))) float f32x4;

// ---- ordered-float <-> uint transforms (ascending float == ascending uint) ----
__device__ __forceinline__ unsigned int f2ord(float f) {
  unsigned int b = __float_as_uint(f);
  return b ^ (((unsigned int)((int)b >> 31)) | 0x80000000u);
}
__device__ __forceinline__ float ord2f(unsigned int u) {
  unsigned int b = u ^ ((~((unsigned int)((int)u >> 31))) | 0x80000000u);
  return __uint_as_float(b);
}
// bf16 round-to-nearest-even
__device__ __forceinline__ unsigned short f2bf(float f) {
  unsigned int u = __float_as_uint(f);
  return (unsigned short)((u + 0x7fffu + ((u >> 16) & 1u)) >> 16);
}

// ---- prep: split codebook into bf16 hi/lo in MFMA-fragment order, w2, zero loss ----
// Fragment layout (short8 units within a stage): unit = ((ct*2+kk)*2+hl)*64 + lane,
// holding W[code=ct*16+(lane&15)][k=kk*32+(lane>>4)*8 + j], j=0..7 as bf16.
__global__ void vq_prep(const float* __restrict__ emb, unsigned short* __restrict__ Wfrag,
                        float* __restrict__ W2, float* __restrict__ out) {
  int t = blockIdx.x * NT + threadIdx.x;   // over HQ*V = 4096
  if (t == 0) out[0] = 0.0f;
  if (t >= HQ * V) return;
  int s = t >> 10, v = t & (V - 1);
  int ct = v >> 4, cl = v & 15;
  const float* e = emb + (size_t)t * D;
  float w2 = 0.0f;
  for (int k = 0; k < D; ++k) {
    float f = e[k];
    w2 += f * f;
    unsigned short hb = f2bf(f);
    float fh = __uint_as_float((unsigned int)hb << 16);
    unsigned short lb = f2bf(f - fh);
    int kk = k >> 5, q = (k >> 3) & 3, j = k & 7;
    size_t base = (((size_t)(s * 64 + ct) * 2 + kk) * 2) * 512
                + (size_t)(q * 16 + cl) * 8 + j;
    Wfrag[base]       = hb;   // hl = 0
    Wfrag[base + 512] = lb;   // hl = 1
  }
  W2[t] = w2;
}

// ---- main kernel: 256 rows/block, 4 waves x 64 rows, MFMA bf16-split, B from L2 ----
// (NT,1): full 512-reg unified budget; (NT,2) capped arch VGPRs at 128 and spilled
// ~260 MB/dispatch (R6-R8). 64 rows/wave halves per-byte B traffic vs 32 and doubles
// compute per load for latency hiding; 2-deep B ping-pong restores prefetch.
__launch_bounds__(NT, 1)
__global__ void vq_main(const float* __restrict__ latent,
                        const float* __restrict__ emb,
                        const unsigned short* __restrict__ Wfrag,
                        const float* __restrict__ W2,
                        float* __restrict__ out) {
  __shared__ float Rt[MR][RT_STRIDE];   // 69.6 KB fp32 residual
  __shared__ int idx_lds[MR];
  __shared__ int n_rescue;
  __shared__ int rescue_rows[MR];
  __shared__ unsigned long long resc_pack[4];   // per-wave rescue winners
  __shared__ float loss_red[NT];

  const int t    = threadIdx.x;
  const int lane = t & 63;
  const int w    = t >> 6;       // wave id: rows [w*64, w*64+64)
  const int cl   = lane & 15;
  const int q    = lane >> 4;
  const size_t row0 = (size_t)blockIdx.x * MR;

  if (t == 0) n_rescue = 0;

  // ---- load latent tile -> Rt (coalesced float4) ----
  {
    const float4* lg = (const float4*)(latent + row0 * D);
    #pragma unroll
    for (int k = 0; k < 16; ++k) {
      int i4 = t + k * NT;                 // 0..4095 float4s
      int row = i4 >> 4, dd = (i4 & 15) * 4;
      *(float4*)&Rt[row][dd] = lg[i4];
    }
  }

  float loss_acc = 0.0f;

  for (int stage = 0; stage < HQ; ++stage) {
    __syncthreads();           // Rt ready (initial load or previous stage's update)

    // ---- build A fragments (bf16 hi/lo) from Rt ----
    short8 Ah[4][2], Al[4][2];
    #pragma unroll
    for (int rt = 0; rt < 4; ++rt)
      #pragma unroll
      for (int kk = 0; kk < 2; ++kk) {
        const float* rp = &Rt[w * 64 + rt * 16 + cl][kk * 32 + q * 8];
        short8 h, l;
        #pragma unroll
        for (int j = 0; j < 8; ++j) {
          float f = rp[j];
          unsigned short hb = f2bf(f);
          float fh = __uint_as_float((unsigned int)hb << 16);
          h[j] = (short)hb;
          l[j] = (short)f2bf(f - fh);
        }
        Ah[rt][kk] = h; Al[rt][kk] = l;
      }

    // per-lane top-2: slot (rt,r) covers row = w*64+rt*16+q*4+r, cols ≡ cl (mod 16)
    float m1[4][4], m2[4][4]; int i1[4][4];
    #pragma unroll
    for (int rt = 0; rt < 4; ++rt)
      #pragma unroll
      for (int r = 0; r < 4; ++r) { m1[rt][r] = INFINITY; m2[rt][r] = INFINITY; i1[rt][r] = 0; }

    const short8* wb = (const short8*)(Wfrag + (size_t)stage * 131072);
    const float* w2p = W2 + stage * V;

    // ---- ct loop: 64 code-tiles; 2-deep ping-pong B prefetch, no barriers ----
    short8 B0[4], B1[4]; float w2a, w2b;
    {
      B0[0] = wb[lane]; B0[1] = wb[lane + 64]; B0[2] = wb[lane + 128]; B0[3] = wb[lane + 192];
      w2a = w2p[cl];
    }
    #pragma unroll 1
    for (int ct = 0; ct < 64; ct += 2) {
      {   // prefetch ct+1
        int base = (ct + 1) * 256 + lane;
        B1[0] = wb[base]; B1[1] = wb[base + 64]; B1[2] = wb[base + 128]; B1[3] = wb[base + 192];
        w2b = w2p[(ct + 1) * 16 + cl];
      }
      {   // compute ct with B0
        int code = ct * 16 + cl;
        #pragma unroll
        for (int rt = 0; rt < 4; ++rt) {
          f32x4 C1 = {0.f,0.f,0.f,0.f}, C2 = {0.f,0.f,0.f,0.f};
          C1 = __builtin_amdgcn_mfma_f32_16x16x32_bf16(Ah[rt][0], B0[0], C1, 0, 0, 0);
          C1 = __builtin_amdgcn_mfma_f32_16x16x32_bf16(Ah[rt][1], B0[2], C1, 0, 0, 0);
          C2 = __builtin_amdgcn_mfma_f32_16x16x32_bf16(Al[rt][0], B0[0], C2, 0, 0, 0);
          C2 = __builtin_amdgcn_mfma_f32_16x16x32_bf16(Al[rt][1], B0[2], C2, 0, 0, 0);
          C2 = __builtin_amdgcn_mfma_f32_16x16x32_bf16(Ah[rt][0], B0[1], C2, 0, 0, 0);
          C2 = __builtin_amdgcn_mfma_f32_16x16x32_bf16(Ah[rt][1], B0[3], C2, 0, 0, 0);
          #pragma unroll
          for (int r = 0; r < 4; ++r) {
            float s = fmaf(-2.0f, C1[r] + C2[r], w2a);
            m2[rt][r] = __builtin_amdgcn_fmed3f(m1[rt][r], s, m2[rt][r]); // new m2
            bool lt = s < m1[rt][r];
            m1[rt][r] = fminf(m1[rt][r], s);
            i1[rt][r] = lt ? code : i1[rt][r];
          }
        }
      }
      {   // prefetch ct+2 (clamped dup at tail: harmless)
        int ctn = (ct + 2 < 64) ? ct + 2 : 63;
        int base = ctn * 256 + lane;
        B0[0] = wb[base]; B0[1] = wb[base + 64]; B0[2] = wb[base + 128]; B0[3] = wb[base + 192];
        w2a = w2p[ctn * 16 + cl];
      }
      {   // compute ct+1 with B1
        int code = (ct + 1) * 16 + cl;
        #pragma unroll
        for (int rt = 0; rt < 4; ++rt) {
          f32x4 C1 = {0.f,0.f,0.f,0.f}, C2 = {0.f,0.f,0.f,0.f};
          C1 = __builtin_amdgcn_mfma_f32_16x16x32_bf16(Ah[rt][0], B1[0], C1, 0, 0, 0);
          C1 = __builtin_amdgcn_mfma_f32_16x16x32_bf16(Ah[rt][1], B1[2], C1, 0, 0, 0);
          C2 = __builtin_amdgcn_mfma_f32_16x16x32_bf16(Al[rt][0], B1[0], C2, 0, 0, 0);
          C2 = __builtin_amdgcn_mfma_f32_16x16x32_bf16(Al[rt][1], B1[2], C2, 0, 0, 0);
          C2 = __builtin_amdgcn_mfma_f32_16x16x32_bf16(Ah[rt][0], B1[1], C2, 0, 0, 0);
          C2 = __builtin_amdgcn_mfma_f32_16x16x32_bf16(Ah[rt][1], B1[3], C2, 0, 0, 0);
          #pragma unroll
          for (int r = 0; r < 4; ++r) {
            float s = fmaf(-2.0f, C1[r] + C2[r], w2b);
            m2[rt][r] = __builtin_amdgcn_fmed3f(m1[rt][r], s, m2[rt][r]);
            bool lt = s < m1[rt][r];
            m1[rt][r] = fminf(m1[rt][r], s);
            i1[rt][r] = lt ? code : i1[rt][r];
          }
        }
      }
    } // ct

    // ---- 16-lane butterfly top-2 reduction ----
    #pragma unroll
    for (int rt = 0; rt < 4; ++rt)
      #pragma unroll
      for (int r = 0; r < 4; ++r) {
        unsigned int phi = f2ord(m1[rt][r]);
        unsigned int plo = (unsigned int)i1[rt][r];
        unsigned int s2  = f2ord(m2[rt][r]);
        #pragma unroll
        for (int mask = 1; mask <= 8; mask <<= 1) {
          unsigned int ohi = (unsigned int)__shfl_xor((int)phi, mask, 16);
          unsigned int olo = (unsigned int)__shfl_xor((int)plo, mask, 16);
          unsigned int os2 = (unsigned int)__shfl_xor((int)s2, mask, 16);
          unsigned long long p  = ((unsigned long long)phi << 32) | plo;
          unsigned long long po = ((unsigned long long)ohi << 32) | olo;
          unsigned int hmax = phi > ohi ? phi : ohi;
          s2 = s2 < os2 ? s2 : os2;
          s2 = s2 < hmax ? s2 : hmax;
          unsigned long long pm = p < po ? p : po;   // ties -> smaller idx (first index)
          phi = (unsigned int)(pm >> 32); plo = (unsigned int)pm;
        }
        if (cl == 0) {
          int row = w * 64 + rt * 16 + q * 4 + r;
          idx_lds[row] = (int)plo;
          float gap = ord2f(s2) - ord2f(phi);
          if (gap < TAU) {
            int slot = atomicAdd(&n_rescue, 1);
            rescue_rows[slot] = row;
          }
        }
      }
    __syncthreads();   // idx_lds + rescue flags visible
    int nres = n_rescue;
    __syncthreads();   // all reads of n_rescue done
    if (t == 0) n_rescue = 0;  // for next stage; ordered by the following barriers

    // ---- near-tie rescue: bit-exact numpy-reference emulation (verified R4/R5) ----
    for (int rr_i = 0; rr_i < nres; ++rr_i) {
      int row = rescue_rows[rr_i];
      float p8[8];
      #pragma unroll
      for (int j = 0; j < 8; ++j) p8[j] = __fmul_rn(Rt[row][j], Rt[row][j]);
      #pragma unroll
      for (int i = 1; i < 8; ++i)
        #pragma unroll
        for (int j = 0; j < 8; ++j)
          p8[j] = __fadd_rn(p8[j], __fmul_rn(Rt[row][8 * i + j], Rt[row][8 * i + j]));
      float rrow = __fadd_rn(__fadd_rn(__fadd_rn(p8[0], p8[1]), __fadd_rn(p8[2], p8[3])),
                             __fadd_rn(__fadd_rn(p8[4], p8[5]), __fadd_rn(p8[6], p8[7])));
      const float* eb = emb + (size_t)stage * V * D;
      float bestd = INFINITY; int besti = 0;
      #pragma unroll
      for (int c = 0; c < 4; ++c) {
        int v = t * 4 + c;
        const float* wv = eb + (size_t)v * D;
        float dot = 0.0f;
        #pragma unroll
        for (int d = 0; d < D; ++d) dot = __fmaf_rn(Rt[row][d], wv[d], dot);
        float q8[8];
        #pragma unroll
        for (int j = 0; j < 8; ++j) q8[j] = __fmul_rn(wv[j], wv[j]);
        #pragma unroll
        for (int i = 1; i < 8; ++i)
          #pragma unroll
          for (int j = 0; j < 8; ++j)
            q8[j] = __fadd_rn(q8[j], __fmul_rn(wv[8 * i + j], wv[8 * i + j]));
        float w2e = __fadd_rn(__fadd_rn(__fadd_rn(q8[0], q8[1]), __fadd_rn(q8[2], q8[3])),
                              __fadd_rn(__fadd_rn(q8[4], q8[5]), __fadd_rn(q8[6], q8[7])));
        float d2 = __fadd_rn(__fsub_rn(rrow, __fmul_rn(2.0f, dot)), w2e);
        if (d2 < bestd) { bestd = d2; besti = v; }
      }
      // parallel argmin: packed (ord(d2)<<32 | v) u64 min == min d2, first-index ties
      unsigned long long pk = ((unsigned long long)f2ord(bestd) << 32) | (unsigned int)besti;
      #pragma unroll
      for (int mask = 1; mask <= 32; mask <<= 1) {
        int lo = (int)(unsigned int)pk, hi = (int)(unsigned int)(pk >> 32);
        int olo = __shfl_xor(lo, mask, 64), ohi = __shfl_xor(hi, mask, 64);
        unsigned long long po = ((unsigned long long)(unsigned int)ohi << 32) | (unsigned int)olo;
        pk = po < pk ? po : pk;
      }
      if (lane == 0) resc_pack[w] = pk;
      __syncthreads();
      if (t == 0) {
        unsigned long long b = resc_pack[0];
        if (resc_pack[1] < b) b = resc_pack[1];
        if (resc_pack[2] < b) b = resc_pack[2];
        if (resc_pack[3] < b) b = resc_pack[3];
        idx_lds[row] = (int)(unsigned int)b;
      }
      __syncthreads();
    }

    // ---- update: r -= q (exact fp32); loss += r_new^2 (one thread per row) ----
    {
      int code = idx_lds[t];
      const float4* qp = (const float4*)(emb + (((size_t)stage * V + code) * D));
      #pragma unroll
      for (int k = 0; k < 16; ++k) {
        float4 qv = qp[k];
        float* rp = &Rt[t][k * 4];
        float r0 = rp[0] - qv.x, r1 = rp[1] - qv.y, r2 = rp[2] - qv.z, r3 = rp[3] - qv.w;
        rp[0] = r0; rp[1] = r1; rp[2] = r2; rp[3] = r3;
        loss_acc += r0 * r0 + r1 * r1 + r2 * r2 + r3 * r3;
      }
    }
    // next stage-top __syncthreads() protects Rt reads-after-write
  } // stages

  __syncthreads();

  // ---- epilogue: quantised = latent - r_final (nontemporal dword stores at out+1) ----
  for (int k = 0; k < 64; ++k) {
    int idx = t + k * NT;                  // 0..16383
    int row = idx >> 6, dd = idx & 63;
    float l = latent[row0 * D + idx];
    __builtin_nontemporal_store(l - Rt[row][dd], &out[1 + row0 * D + idx]);
  }

  // ---- loss reduction + atomic ----
  loss_red[t] = loss_acc;
  __syncthreads();
  for (int s = NT / 2; s > 0; s >>= 1) {
    if (t < s) loss_red[t] += loss_red[t + s];
    __syncthreads();
  }
  if (t == 0) atomicAdd(out, loss_red[0] * LOSS_SCALE);
}

extern "C" void kernel_launch(void* const* d_in, const int* in_sizes, int n_in,
                              void* d_out, int out_size, void* d_ws, size_t ws_size,
                              hipStream_t stream) {
  const float* latent = (const float*)d_in[0];
  const float* emb    = (const float*)d_in[1];
  float* out = (float*)d_out;

  unsigned short* Wfrag = (unsigned short*)d_ws;            // HQ*V*D*2 ushorts = 1 MB
  float* W2 = (float*)(Wfrag + (size_t)HQ * V * D * 2);     // HQ*V floats = 16 KB

  vq_prep<<<(HQ * V + NT - 1) / NT, NT, 0, stream>>>(emb, Wfrag, W2, out);
  vq_main<<<M_TOTAL / MR, NT, 0, stream>>>(latent, emb, Wfrag, W2, out);
}